// Round 3
// baseline (253.052 us; speedup 1.0000x reference)
//
#include <hip/hip_runtime.h>
#include <math.h>

typedef float f2 __attribute__((ext_vector_type(2)));

// Problem constants
constexpr int NB = 64;      // batch
constexpr int NU = 2048;    // U
constexpr int ND = 1024;    // dec dim
constexpr int NE = 512;     // enc dim
constexpr int NH = 4;       // heads
constexpr int NK = 256;     // head dim
constexpr int NA = 1024;    // out dim
constexpr int NS = 16;      // U splits
constexpr int ROWS_PER_BLOCK = NU / NS;            // 128
constexpr int ROWS_PER_WAVE  = ROWS_PER_BLOCK / 4; // 32
constexpr float SCALE = 0.0625f;                   // 1/sqrt(256)

constexpr int RSPLIT = 16;
constexpr int RCH = (NH*NE)/RSPLIT;  // 128
constexpr int BT = 8;

constexpr int DSP = 16;   // D splits in k_phi (64 d each)

// workspace layout (float offsets)
constexpr size_t WS_Q   = 0;                            // q:      131072 floats
constexpr size_t WS_CTX = WS_Q + (size_t)NB*NH*NE;      // ctxacc: 131072 floats
constexpr size_t WS_P   = WS_CTX + (size_t)NB*NH*NE;    // phi partials: 16*64*4*256 = 1M floats

// ---------------------------------------------------------------------------
// K1a: phi partials. (unchanged this round)
__global__ __launch_bounds__(256) void k_phi(
    const float* __restrict__ dec, const float* __restrict__ phi_w,
    float* __restrict__ P, float* __restrict__ q, float* __restrict__ ctxacc,
    const float* __restrict__ out_b, float* __restrict__ out)
{
  const int flat = blockIdx.x;              // 0..255
  const int kc = flat & 3;
  const int h  = (flat >> 2) & 3;
  const int ds = flat >> 4;                 // 0..15
  const int t = threadIdx.x;

  // replay-safe inits (consumed by later kernels; kernel boundary orders them)
  ctxacc[(size_t)flat*512 + t]       = 0.f;
  ctxacc[(size_t)flat*512 + 256 + t] = 0.f;
  q[(size_t)flat*512 + t]            = 0.f;
  q[(size_t)flat*512 + 256 + t]      = 0.f;
  out[(size_t)flat*256 + t] = out_b[(flat*256 + t) & (NA-1)];

  const int d0 = ds*64, k0 = kc*64;

  __shared__ float phi_lds[64][64];   // 16 KB [d][k]
  __shared__ float dec_t[64][68];     // 17 KB [d][b]

  {
    const int kq = t & 15, r = t >> 4;        // r: 0..15
    const float* pwb = phi_w + ((size_t)h*ND + d0)*NK + k0;
    #pragma unroll
    for (int p = 0; p < 4; ++p) {
      float4 v = *(const float4*)(pwb + (size_t)(r + 16*p)*NK + 4*kq);
      *(float4*)&phi_lds[r + 16*p][4*kq] = v;
    }
    const float* db = dec + d0 + 4*kq;
    #pragma unroll
    for (int p = 0; p < 4; ++p) {
      const int b = r + 16*p;
      float4 v = *(const float4*)(db + (size_t)b*ND);
      dec_t[4*kq+0][b] = v.x; dec_t[4*kq+1][b] = v.y;
      dec_t[4*kq+2][b] = v.z; dec_t[4*kq+3][b] = v.w;
    }
  }
  __syncthreads();

  const int k = t & 63, bq = t >> 6, b0 = bq*16;
  f2 acc2[8];
  #pragma unroll
  for (int i = 0; i < 8; ++i) acc2[i] = f2{0.f, 0.f};
  #pragma unroll 4
  for (int d = 0; d < 64; ++d) {
    float w = phi_lds[d][k];
    f2 ww = f2{w, w};
    float4 a0 = *(const float4*)&dec_t[d][b0];
    float4 a1 = *(const float4*)&dec_t[d][b0+4];
    float4 a2 = *(const float4*)&dec_t[d][b0+8];
    float4 a3 = *(const float4*)&dec_t[d][b0+12];
    acc2[0] += f2{a0.x,a0.y}*ww; acc2[1] += f2{a0.z,a0.w}*ww;
    acc2[2] += f2{a1.x,a1.y}*ww; acc2[3] += f2{a1.z,a1.w}*ww;
    acc2[4] += f2{a2.x,a2.y}*ww; acc2[5] += f2{a2.z,a2.w}*ww;
    acc2[6] += f2{a3.x,a3.y}*ww; acc2[7] += f2{a3.z,a3.w}*ww;
  }
  float* pb = P + (((size_t)ds*64 + b0)*NH + h)*NK + k0 + k;
  #pragma unroll
  for (int j = 0; j < 8; ++j) {
    pb[(size_t)(2*j  )*NH*NK] = acc2[j][0];
    pb[(size_t)(2*j+1)*NH*NK] = acc2[j][1];
  }
}

// ---------------------------------------------------------------------------
// K1b: (unchanged this round)
__global__ __launch_bounds__(256) void k_q(
    const float* __restrict__ P, const float* __restrict__ phi_b,
    const float* __restrict__ psi_w, float* __restrict__ q)
{
  const int flat = blockIdx.x;              // 0..127
  const int ks = flat & 3;
  const int ec = (flat >> 2) & 7;
  const int h  = flat >> 5;
  const int t = threadIdx.x;
  const int k0 = ks*64, e0 = ec*64;

  __shared__ float phi_red[64][68];   // [k][b]
  __shared__ float psi_lds[64][65];   // [e][k]

  {
    const int e = t >> 2, kq4 = t & 3;
    const float* pb = psi_w + ((size_t)h*NE + e0 + e)*NK + k0 + 4*kq4;
    #pragma unroll
    for (int p = 0; p < 4; ++p) {
      float4 v = *(const float4*)(pb + 16*p);
      const int kk = 4*(kq4 + 4*p);
      psi_lds[e][kk+0] = v.x; psi_lds[e][kk+1] = v.y;
      psi_lds[e][kk+2] = v.z; psi_lds[e][kk+3] = v.w;
    }
  }
  {
    const int b = t >> 2, kq4 = t & 3;
    const float* pbase = P + ((size_t)b*NH + h)*NK + k0 + 4*kq4;
    #pragma unroll
    for (int p = 0; p < 4; ++p) {
      float4 s = make_float4(0.f, 0.f, 0.f, 0.f);
      #pragma unroll
      for (int dsi = 0; dsi < DSP; ++dsi) {
        float4 v = *(const float4*)(pbase + (size_t)dsi*64*NH*NK + 16*p);
        s.x += v.x; s.y += v.y; s.z += v.z; s.w += v.w;
      }
      const int kk = 4*(kq4 + 4*p);
      const float* bb = phi_b + h*NK + k0 + kk;
      phi_red[kk+0][b] = s.x + bb[0];
      phi_red[kk+1][b] = s.y + bb[1];
      phi_red[kk+2][b] = s.z + bb[2];
      phi_red[kk+3][b] = s.w + bb[3];
    }
  }
  __syncthreads();

  const int e = t & 63, bq = t >> 6, b0 = bq*16;
  f2 acc2[8];
  #pragma unroll
  for (int i = 0; i < 8; ++i) acc2[i] = f2{0.f, 0.f};
  #pragma unroll 4
  for (int kl = 0; kl < 64; ++kl) {
    float w = psi_lds[e][kl];
    f2 ww = f2{w, w};
    float4 a0 = *(const float4*)&phi_red[kl][b0];
    float4 a1 = *(const float4*)&phi_red[kl][b0+4];
    float4 a2 = *(const float4*)&phi_red[kl][b0+8];
    float4 a3 = *(const float4*)&phi_red[kl][b0+12];
    acc2[0] += f2{a0.x,a0.y}*ww; acc2[1] += f2{a0.z,a0.w}*ww;
    acc2[2] += f2{a1.x,a1.y}*ww; acc2[3] += f2{a1.z,a1.w}*ww;
    acc2[4] += f2{a2.x,a2.y}*ww; acc2[5] += f2{a2.z,a2.w}*ww;
    acc2[6] += f2{a3.x,a3.y}*ww; acc2[7] += f2{a3.z,a3.w}*ww;
  }
  float* qb = q + ((size_t)b0*NH + h)*NE + e0 + e;
  #pragma unroll
  for (int j = 0; j < 8; ++j) {
    unsafeAtomicAdd(qb + (size_t)(2*j  )*NH*NE, acc2[j][0]);
    unsafeAtomicAdd(qb + (size_t)(2*j+1)*NH*NE, acc2[j][1]);
  }
}

// ---------------------------------------------------------------------------
// K2 v2: 4-row register pipeline (8 loads in flight), head-packed f2
// butterflies (2 packed chains/row, 4 chains interleaved per pair -> DS
// latency overlapped), SCALE pre-folded into q.
__device__ __forceinline__ f2 shflx(f2 v, int m) {
  return f2{__shfl_xor(v[0], m), __shfl_xor(v[1], m)};
}
__device__ __forceinline__ float dot8(const f2* qh, f2 e0, f2 e1, f2 e2, f2 e3) {
  f2 p = e0*qh[0] + e1*qh[1] + e2*qh[2] + e3*qh[3];
  return p[0] + p[1];
}

__global__ __launch_bounds__(256, 4) void k_flash(
    const float* __restrict__ enc, const float* __restrict__ qg,
    float* __restrict__ ctxacc)
{
  const int s = blockIdx.x;
  const int b = blockIdx.y;
  const int t = threadIdx.x;
  const int wave = t >> 6;
  const int lane = t & 63;

  // q fragments, SCALE folded in: lane owns cols {4l..4l+3} and {256+4l..}
  f2 qv[NH][4];
  const float* qb = qg + (size_t)b*NH*NE;
  #pragma unroll
  for (int h = 0; h < NH; ++h) {
    float4 a0 = *(const float4*)(qb + h*NE + 4*lane);
    float4 a1 = *(const float4*)(qb + h*NE + 256 + 4*lane);
    qv[h][0] = f2{a0.x*SCALE, a0.y*SCALE}; qv[h][1] = f2{a0.z*SCALE, a0.w*SCALE};
    qv[h][2] = f2{a1.x*SCALE, a1.y*SCALE}; qv[h][3] = f2{a1.z*SCALE, a1.w*SCALE};
  }
  f2 acc2[NH][4];
  #pragma unroll
  for (int h = 0; h < NH; ++h)
    #pragma unroll
    for (int j = 0; j < 4; ++j) acc2[h][j] = f2{0.f, 0.f};

  const int u0 = s*ROWS_PER_BLOCK + wave*ROWS_PER_WAVE;
  const float* encb = enc + ((size_t)b*NU + u0)*NE;

#define LOADR(d0, d1, R) { \
    d0 = *(const float4*)(encb + (size_t)(R)*NE + 4*lane); \
    d1 = *(const float4*)(encb + (size_t)(R)*NE + 256 + 4*lane); }

// Process rows X (xe*) and Y (ye*) together: 4 packed butterfly chains
// interleaved so the 6-step DS latency overlaps across chains.
#define ROWPAIR(X0, X1, Y0, Y1) { \
    f2 xe0=f2{X0.x,X0.y}, xe1=f2{X0.z,X0.w}, xe2=f2{X1.x,X1.y}, xe3=f2{X1.z,X1.w}; \
    f2 ye0=f2{Y0.x,Y0.y}, ye1=f2{Y0.z,Y0.w}, ye2=f2{Y1.x,Y1.y}, ye3=f2{Y1.z,Y1.w}; \
    f2 xd01 = f2{dot8(qv[0],xe0,xe1,xe2,xe3), dot8(qv[1],xe0,xe1,xe2,xe3)}; \
    f2 xd23 = f2{dot8(qv[2],xe0,xe1,xe2,xe3), dot8(qv[3],xe0,xe1,xe2,xe3)}; \
    f2 yd01 = f2{dot8(qv[0],ye0,ye1,ye2,ye3), dot8(qv[1],ye0,ye1,ye2,ye3)}; \
    f2 yd23 = f2{dot8(qv[2],ye0,ye1,ye2,ye3), dot8(qv[3],ye0,ye1,ye2,ye3)}; \
    _Pragma("unroll") \
    for (int off = 1; off < 64; off <<= 1) { \
      xd01 += shflx(xd01, off); xd23 += shflx(xd23, off); \
      yd01 += shflx(yd01, off); yd23 += shflx(yd23, off); \
    } \
    float xw0=__expf(xd01[0]), xw1=__expf(xd01[1]); \
    float xw2=__expf(xd23[0]), xw3=__expf(xd23[1]); \
    float yw0=__expf(yd01[0]), yw1=__expf(yd01[1]); \
    float yw2=__expf(yd23[0]), yw3=__expf(yd23[1]); \
    acc2[0][0]+=f2{xw0,xw0}*xe0; acc2[0][1]+=f2{xw0,xw0}*xe1; \
    acc2[0][2]+=f2{xw0,xw0}*xe2; acc2[0][3]+=f2{xw0,xw0}*xe3; \
    acc2[1][0]+=f2{xw1,xw1}*xe0; acc2[1][1]+=f2{xw1,xw1}*xe1; \
    acc2[1][2]+=f2{xw1,xw1}*xe2; acc2[1][3]+=f2{xw1,xw1}*xe3; \
    acc2[2][0]+=f2{xw2,xw2}*xe0; acc2[2][1]+=f2{xw2,xw2}*xe1; \
    acc2[2][2]+=f2{xw2,xw2}*xe2; acc2[2][3]+=f2{xw2,xw2}*xe3; \
    acc2[3][0]+=f2{xw3,xw3}*xe0; acc2[3][1]+=f2{xw3,xw3}*xe1; \
    acc2[3][2]+=f2{xw3,xw3}*xe2; acc2[3][3]+=f2{xw3,xw3}*xe3; \
    acc2[0][0]+=f2{yw0,yw0}*ye0; acc2[0][1]+=f2{yw0,yw0}*ye1; \
    acc2[0][2]+=f2{yw0,yw0}*ye2; acc2[0][3]+=f2{yw0,yw0}*ye3; \
    acc2[1][0]+=f2{yw1,yw1}*ye0; acc2[1][1]+=f2{yw1,yw1}*ye1; \
    acc2[1][2]+=f2{yw1,yw1}*ye2; acc2[1][3]+=f2{yw1,yw1}*ye3; \
    acc2[2][0]+=f2{yw2,yw2}*ye0; acc2[2][1]+=f2{yw2,yw2}*ye1; \
    acc2[2][2]+=f2{yw2,yw2}*ye2; acc2[2][3]+=f2{yw2,yw2}*ye3; \
    acc2[3][0]+=f2{yw3,yw3}*ye0; acc2[3][1]+=f2{yw3,yw3}*ye1; \
    acc2[3][2]+=f2{yw3,yw3}*ye2; acc2[3][3]+=f2{yw3,yw3}*ye3; }

  float4 A0,A1,B0,B1,C0,C1,D0,D1;
  LOADR(A0,A1,0) LOADR(B0,B1,1) LOADR(C0,C1,2) LOADR(D0,D1,3)
  #pragma unroll 2
  for (int r = 0; r < ROWS_PER_WAVE; r += 4) {
    ROWPAIR(A0,A1,B0,B1);
    if (r + 5 < ROWS_PER_WAVE) { LOADR(A0,A1,r+4) LOADR(B0,B1,r+5) }
    ROWPAIR(C0,C1,D0,D1);
    if (r + 7 < ROWS_PER_WAVE) { LOADR(C0,C1,r+6) LOADR(D0,D1,r+7) }
  }
#undef LOADR
#undef ROWPAIR

  __shared__ float acc_lds[4][NH][NE];   // 32 KB
  #pragma unroll
  for (int h = 0; h < NH; ++h) {
    *(float4*)&acc_lds[wave][h][4*lane] =
        make_float4(acc2[h][0][0], acc2[h][0][1], acc2[h][1][0], acc2[h][1][1]);
    *(float4*)&acc_lds[wave][h][256 + 4*lane] =
        make_float4(acc2[h][2][0], acc2[h][2][1], acc2[h][3][0], acc2[h][3][1]);
  }
  __syncthreads();
  float* cb = ctxacc + (size_t)b*(NH*NE);
  #pragma unroll
  for (int h = 0; h < NH; ++h) {
    #pragma unroll
    for (int eo = 0; eo < 2; ++eo) {
      int e = t + eo*256;
      float v = acc_lds[0][h][e] + acc_lds[1][h][e] + acc_lds[2][h][e] + acc_lds[3][h][e];
      unsafeAtomicAdd(&cb[h*NE + e], v);
    }
  }
}

// ---------------------------------------------------------------------------
// K3: (unchanged this round)
__global__ __launch_bounds__(256) void k_out(
    const float* __restrict__ ctxacc, const float* __restrict__ out_w,
    float* __restrict__ out)
{
  const int t = threadIdx.x;
  const int a = blockIdx.x*256 + t;
  const int b0 = blockIdx.y * BT;
  const int rc = blockIdx.z;
  const int h  = rc >> 2;
  const int e0 = (rc & 3) * RCH;

  __shared__ float rn_lds[BT];
  const int wv = t >> 6, lane = t & 63;
  {
    const int i = 2*wv + (lane >> 5);
    const int l32 = lane & 31;
    const float* row = ctxacc + (size_t)(b0+i)*(NH*NE) + (size_t)h*NE;
    float ss = 0.f;
    #pragma unroll
    for (int j = 0; j < 16; ++j) { float v = row[l32 + 32*j]; ss += v*v; }
    #pragma unroll
    for (int off = 1; off < 32; off <<= 1) ss += __shfl_xor(ss, off);
    if (l32 == 0) rn_lds[i] = rsqrtf(fmaxf(ss, 1e-12f));
  }
  __syncthreads();

  __shared__ float c_lds[RCH][BT];   // 4 KB
  for (int g = t; g < RCH*BT; g += 256) {
    const int r = g & (RCH-1), i = g >> 7;
    c_lds[r][i] = ctxacc[(size_t)(b0+i)*(NH*NE) + (size_t)h*NE + e0 + r] * rn_lds[i];
  }
  __syncthreads();

  float accv[BT];
  #pragma unroll
  for (int i = 0; i < BT; ++i) accv[i] = 0.f;
  const float* w = out_w + ((size_t)rc*RCH)*NA + a;
  #pragma unroll 8
  for (int r = 0; r < RCH; ++r) {
    float wvv = w[(size_t)r*NA];
    float4 ca = *(const float4*)&c_lds[r][0];
    float4 cb = *(const float4*)&c_lds[r][4];
    accv[0] += ca.x*wvv; accv[1] += ca.y*wvv; accv[2] += ca.z*wvv; accv[3] += ca.w*wvv;
    accv[4] += cb.x*wvv; accv[5] += cb.y*wvv; accv[6] += cb.z*wvv; accv[7] += cb.w*wvv;
  }
  #pragma unroll
  for (int i = 0; i < BT; ++i)
    unsafeAtomicAdd(&out[(size_t)(b0+i)*NA + a], accv[i]);
}

// ---------------------------------------------------------------------------
extern "C" void kernel_launch(void* const* d_in, const int* in_sizes, int n_in,
                              void* d_out, int out_size, void* d_ws, size_t ws_size,
                              hipStream_t stream) {
  const float* dec   = (const float*)d_in[0];
  const float* enc   = (const float*)d_in[1];
  const float* phi_w = (const float*)d_in[2];
  const float* phi_b = (const float*)d_in[3];
  const float* psi_w = (const float*)d_in[4];
  // d_in[5] = psi_b: constant over u -> cancels in softmax.
  const float* out_w = (const float*)d_in[6];
  const float* out_b = (const float*)d_in[7];
  float* out = (float*)d_out;
  float* ws = (float*)d_ws;
  float* q      = ws + WS_Q;
  float* ctxacc = ws + WS_CTX;
  float* P      = ws + WS_P;

  hipLaunchKernelGGL(k_phi,   dim3(NH*4*DSP),              dim3(256), 0, stream,
                     dec, phi_w, P, q, ctxacc, out_b, out);
  hipLaunchKernelGGL(k_q,     dim3(128),                   dim3(256), 0, stream,
                     P, phi_b, psi_w, q);
  hipLaunchKernelGGL(k_flash, dim3(NS, NB),                dim3(256), 0, stream,
                     enc, q, ctxacc);
  hipLaunchKernelGGL(k_out,   dim3(NA/256, NB/BT, RSPLIT), dim3(256), 0, stream,
                     ctxacc, out_w, out);
}

// Round 4
// 91.179 us; speedup vs baseline: 2.7753x; 2.7753x over previous
//
#include <hip/hip_runtime.h>
#include <math.h>

typedef float f2 __attribute__((ext_vector_type(2)));

// Problem constants
constexpr int NB = 64;      // batch
constexpr int NU = 2048;    // U
constexpr int ND = 1024;    // dec dim
constexpr int NE = 512;     // enc dim
constexpr int NH = 4;       // heads
constexpr int NK = 256;     // head dim
constexpr int NA = 1024;    // out dim
constexpr int NS = 16;      // U splits
constexpr int ROWS_PER_BLOCK = NU / NS;            // 128
constexpr int ROWS_PER_WAVE  = ROWS_PER_BLOCK / 4; // 32
constexpr float SCALE = 0.0625f;                   // 1/sqrt(256)

constexpr int RSPLIT = 16;
constexpr int RCH = (NH*NE)/RSPLIT;  // 128
constexpr int BT = 8;

constexpr int DSP = 16;   // D splits in k_phi (64 d each)

// workspace layout (float offsets)
constexpr size_t WS_Q   = 0;                            // q:      131072 floats
constexpr size_t WS_CTX = WS_Q + (size_t)NB*NH*NE;      // ctxacc: 131072 floats
constexpr size_t WS_P   = WS_CTX + (size_t)NB*NH*NE;    // phi partials: 16*64*4*256 = 1M floats

// ---------------------------------------------------------------------------
// K1a: phi partials. (unchanged)
__global__ __launch_bounds__(256) void k_phi(
    const float* __restrict__ dec, const float* __restrict__ phi_w,
    float* __restrict__ P, float* __restrict__ q, float* __restrict__ ctxacc,
    const float* __restrict__ out_b, float* __restrict__ out)
{
  const int flat = blockIdx.x;              // 0..255
  const int kc = flat & 3;
  const int h  = (flat >> 2) & 3;
  const int ds = flat >> 4;                 // 0..15
  const int t = threadIdx.x;

  // replay-safe inits (consumed by later kernels; kernel boundary orders them)
  ctxacc[(size_t)flat*512 + t]       = 0.f;
  ctxacc[(size_t)flat*512 + 256 + t] = 0.f;
  q[(size_t)flat*512 + t]            = 0.f;
  q[(size_t)flat*512 + 256 + t]      = 0.f;
  out[(size_t)flat*256 + t] = out_b[(flat*256 + t) & (NA-1)];

  const int d0 = ds*64, k0 = kc*64;

  __shared__ float phi_lds[64][64];   // 16 KB [d][k]
  __shared__ float dec_t[64][68];     // 17 KB [d][b]

  {
    const int kq = t & 15, r = t >> 4;        // r: 0..15
    const float* pwb = phi_w + ((size_t)h*ND + d0)*NK + k0;
    #pragma unroll
    for (int p = 0; p < 4; ++p) {
      float4 v = *(const float4*)(pwb + (size_t)(r + 16*p)*NK + 4*kq);
      *(float4*)&phi_lds[r + 16*p][4*kq] = v;
    }
    const float* db = dec + d0 + 4*kq;
    #pragma unroll
    for (int p = 0; p < 4; ++p) {
      const int b = r + 16*p;
      float4 v = *(const float4*)(db + (size_t)b*ND);
      dec_t[4*kq+0][b] = v.x; dec_t[4*kq+1][b] = v.y;
      dec_t[4*kq+2][b] = v.z; dec_t[4*kq+3][b] = v.w;
    }
  }
  __syncthreads();

  const int k = t & 63, bq = t >> 6, b0 = bq*16;
  f2 acc2[8];
  #pragma unroll
  for (int i = 0; i < 8; ++i) acc2[i] = f2{0.f, 0.f};
  #pragma unroll 4
  for (int d = 0; d < 64; ++d) {
    float w = phi_lds[d][k];
    f2 ww = f2{w, w};
    float4 a0 = *(const float4*)&dec_t[d][b0];
    float4 a1 = *(const float4*)&dec_t[d][b0+4];
    float4 a2 = *(const float4*)&dec_t[d][b0+8];
    float4 a3 = *(const float4*)&dec_t[d][b0+12];
    acc2[0] += f2{a0.x,a0.y}*ww; acc2[1] += f2{a0.z,a0.w}*ww;
    acc2[2] += f2{a1.x,a1.y}*ww; acc2[3] += f2{a1.z,a1.w}*ww;
    acc2[4] += f2{a2.x,a2.y}*ww; acc2[5] += f2{a2.z,a2.w}*ww;
    acc2[6] += f2{a3.x,a3.y}*ww; acc2[7] += f2{a3.z,a3.w}*ww;
  }
  float* pb = P + (((size_t)ds*64 + b0)*NH + h)*NK + k0 + k;
  #pragma unroll
  for (int j = 0; j < 8; ++j) {
    pb[(size_t)(2*j  )*NH*NK] = acc2[j][0];
    pb[(size_t)(2*j+1)*NH*NK] = acc2[j][1];
  }
}

// ---------------------------------------------------------------------------
// K1b: (unchanged)
__global__ __launch_bounds__(256) void k_q(
    const float* __restrict__ P, const float* __restrict__ phi_b,
    const float* __restrict__ psi_w, float* __restrict__ q)
{
  const int flat = blockIdx.x;              // 0..127
  const int ks = flat & 3;
  const int ec = (flat >> 2) & 7;
  const int h  = flat >> 5;
  const int t = threadIdx.x;
  const int k0 = ks*64, e0 = ec*64;

  __shared__ float phi_red[64][68];   // [k][b]
  __shared__ float psi_lds[64][65];   // [e][k]

  {
    const int e = t >> 2, kq4 = t & 3;
    const float* pb = psi_w + ((size_t)h*NE + e0 + e)*NK + k0 + 4*kq4;
    #pragma unroll
    for (int p = 0; p < 4; ++p) {
      float4 v = *(const float4*)(pb + 16*p);
      const int kk = 4*(kq4 + 4*p);
      psi_lds[e][kk+0] = v.x; psi_lds[e][kk+1] = v.y;
      psi_lds[e][kk+2] = v.z; psi_lds[e][kk+3] = v.w;
    }
  }
  {
    const int b = t >> 2, kq4 = t & 3;
    const float* pbase = P + ((size_t)b*NH + h)*NK + k0 + 4*kq4;
    #pragma unroll
    for (int p = 0; p < 4; ++p) {
      float4 s = make_float4(0.f, 0.f, 0.f, 0.f);
      #pragma unroll
      for (int dsi = 0; dsi < DSP; ++dsi) {
        float4 v = *(const float4*)(pbase + (size_t)dsi*64*NH*NK + 16*p);
        s.x += v.x; s.y += v.y; s.z += v.z; s.w += v.w;
      }
      const int kk = 4*(kq4 + 4*p);
      const float* bb = phi_b + h*NK + k0 + kk;
      phi_red[kk+0][b] = s.x + bb[0];
      phi_red[kk+1][b] = s.y + bb[1];
      phi_red[kk+2][b] = s.z + bb[2];
      phi_red[kk+3][b] = s.w + bb[3];
    }
  }
  __syncthreads();

  const int e = t & 63, bq = t >> 6, b0 = bq*16;
  f2 acc2[8];
  #pragma unroll
  for (int i = 0; i < 8; ++i) acc2[i] = f2{0.f, 0.f};
  #pragma unroll 4
  for (int kl = 0; kl < 64; ++kl) {
    float w = psi_lds[e][kl];
    f2 ww = f2{w, w};
    float4 a0 = *(const float4*)&phi_red[kl][b0];
    float4 a1 = *(const float4*)&phi_red[kl][b0+4];
    float4 a2 = *(const float4*)&phi_red[kl][b0+8];
    float4 a3 = *(const float4*)&phi_red[kl][b0+12];
    acc2[0] += f2{a0.x,a0.y}*ww; acc2[1] += f2{a0.z,a0.w}*ww;
    acc2[2] += f2{a1.x,a1.y}*ww; acc2[3] += f2{a1.z,a1.w}*ww;
    acc2[4] += f2{a2.x,a2.y}*ww; acc2[5] += f2{a2.z,a2.w}*ww;
    acc2[6] += f2{a3.x,a3.y}*ww; acc2[7] += f2{a3.z,a3.w}*ww;
  }
  float* qb = q + ((size_t)b0*NH + h)*NE + e0 + e;
  #pragma unroll
  for (int j = 0; j < 8; ++j) {
    unsafeAtomicAdd(qb + (size_t)(2*j  )*NH*NE, acc2[j][0]);
    unsafeAtomicAdd(qb + (size_t)(2*j+1)*NH*NE, acc2[j][1]);
  }
}

// ---------------------------------------------------------------------------
// K2 v3: decouple streaming from the dependent chain. Each wave double-buffers
// 2-row (4 KB) chunks of enc into wave-private LDS via global_load_lds
// (contiguous copy, counted vmcnt(4) -> loads always in flight), computes
// from LDS with the round-2-measured row body. acc reduce reuses the
// staging LDS (32 KB total).
__global__ __launch_bounds__(256) void k_flash(
    const float* __restrict__ enc, const float* __restrict__ qg,
    float* __restrict__ ctxacc)
{
  const int s = blockIdx.x;
  const int b = blockIdx.y;
  const int t = threadIdx.x;
  const int wave = t >> 6;
  const int lane = t & 63;

  __shared__ float sbuf[4][2][2*NE];   // [wave][buf][2 rows x 512] = 32 KB

  // q fragments, SCALE folded in: lane owns cols {4l..4l+3} and {256+4l..}
  f2 qv[NH][4];
  const float* qb = qg + (size_t)b*NH*NE;
  #pragma unroll
  for (int h = 0; h < NH; ++h) {
    float4 a0 = *(const float4*)(qb + h*NE + 4*lane);
    float4 a1 = *(const float4*)(qb + h*NE + 256 + 4*lane);
    qv[h][0] = f2{a0.x*SCALE, a0.y*SCALE}; qv[h][1] = f2{a0.z*SCALE, a0.w*SCALE};
    qv[h][2] = f2{a1.x*SCALE, a1.y*SCALE}; qv[h][3] = f2{a1.z*SCALE, a1.w*SCALE};
  }
  f2 acc2[NH][4];
  #pragma unroll
  for (int h = 0; h < NH; ++h)
    #pragma unroll
    for (int j = 0; j < 4; ++j) acc2[h][j] = f2{0.f, 0.f};

  const int u0 = s*ROWS_PER_BLOCK + wave*ROWS_PER_WAVE;
  const float* encb = enc + ((size_t)b*NU + u0)*NE;

  // stage chunk c (rows 2c, 2c+1 of this wave; 4 KB contiguous) into buf
  // global src is per-lane (base + lane*16B); LDS dst is wave-uniform base,
  // HW adds lane*16 -> linear layout matches compute reads.
  auto STAGE = [&](int c, int buf) {
    const float* src = encb + (size_t)c*2*NE + 4*lane;
    float* dst = &sbuf[wave][buf][0];
    #pragma unroll
    for (int i = 0; i < 4; ++i) {
      __builtin_amdgcn_global_load_lds(
          (const __attribute__((address_space(1))) void*)(src + i*256),
          (__attribute__((address_space(3))) void*)(dst + i*256),
          16, 0, 0);
    }
  };

  STAGE(0, 0);
  int cur = 0;
  for (int c = 0; c < ROWS_PER_WAVE/2; ++c) {
    if (c < ROWS_PER_WAVE/2 - 1) {
      STAGE(c+1, cur^1);
      asm volatile("s_waitcnt vmcnt(4)" ::: "memory");   // chunk c landed
    } else {
      asm volatile("s_waitcnt vmcnt(0)" ::: "memory");
    }
    __builtin_amdgcn_sched_barrier(0);
    const float* rowbase = &sbuf[wave][cur][0];
    #pragma unroll
    for (int rr = 0; rr < 2; ++rr) {
      float4 v0 = *(const float4*)(rowbase + rr*NE + 4*lane);
      float4 v1 = *(const float4*)(rowbase + rr*NE + 256 + 4*lane);
      f2 e0 = f2{v0.x, v0.y}, e1 = f2{v0.z, v0.w};
      f2 e2 = f2{v1.x, v1.y}, e3 = f2{v1.z, v1.w};
      float d[NH];
      #pragma unroll
      for (int h = 0; h < NH; ++h) {
        f2 p = e0*qv[h][0] + e1*qv[h][1] + e2*qv[h][2] + e3*qv[h][3];
        d[h] = p[0] + p[1];
      }
      #pragma unroll
      for (int off = 1; off < 64; off <<= 1) {
        #pragma unroll
        for (int h = 0; h < NH; ++h) d[h] += __shfl_xor(d[h], off);
      }
      #pragma unroll
      for (int h = 0; h < NH; ++h) {
        float pf = __expf(d[h]);
        f2 pp = f2{pf, pf};
        acc2[h][0] += pp*e0; acc2[h][1] += pp*e1;
        acc2[h][2] += pp*e2; acc2[h][3] += pp*e3;
      }
    }
    cur ^= 1;
  }

  // cross-wave reduce: reuse sbuf as acc_lds[4][NH][NE] (32 KB)
  __syncthreads();   // all waves done reading their sbuf region
  float* acc_lds = &sbuf[0][0][0];
  #pragma unroll
  for (int h = 0; h < NH; ++h) {
    *(float4*)&acc_lds[(wave*NH + h)*NE + 4*lane] =
        make_float4(acc2[h][0][0], acc2[h][0][1], acc2[h][1][0], acc2[h][1][1]);
    *(float4*)&acc_lds[(wave*NH + h)*NE + 256 + 4*lane] =
        make_float4(acc2[h][2][0], acc2[h][2][1], acc2[h][3][0], acc2[h][3][1]);
  }
  __syncthreads();
  float* cb = ctxacc + (size_t)b*(NH*NE);
  #pragma unroll
  for (int h = 0; h < NH; ++h) {
    #pragma unroll
    for (int eo = 0; eo < 2; ++eo) {
      int e = t + eo*256;
      float v = acc_lds[(0*NH + h)*NE + e] + acc_lds[(1*NH + h)*NE + e]
              + acc_lds[(2*NH + h)*NE + e] + acc_lds[(3*NH + h)*NE + e];
      unsafeAtomicAdd(&cb[h*NE + e], v);
    }
  }
}

// ---------------------------------------------------------------------------
// K3: (unchanged)
__global__ __launch_bounds__(256) void k_out(
    const float* __restrict__ ctxacc, const float* __restrict__ out_w,
    float* __restrict__ out)
{
  const int t = threadIdx.x;
  const int a = blockIdx.x*256 + t;
  const int b0 = blockIdx.y * BT;
  const int rc = blockIdx.z;
  const int h  = rc >> 2;
  const int e0 = (rc & 3) * RCH;

  __shared__ float rn_lds[BT];
  const int wv = t >> 6, lane = t & 63;
  {
    const int i = 2*wv + (lane >> 5);
    const int l32 = lane & 31;
    const float* row = ctxacc + (size_t)(b0+i)*(NH*NE) + (size_t)h*NE;
    float ss = 0.f;
    #pragma unroll
    for (int j = 0; j < 16; ++j) { float v = row[l32 + 32*j]; ss += v*v; }
    #pragma unroll
    for (int off = 1; off < 32; off <<= 1) ss += __shfl_xor(ss, off);
    if (l32 == 0) rn_lds[i] = rsqrtf(fmaxf(ss, 1e-12f));
  }
  __syncthreads();

  __shared__ float c_lds[RCH][BT];   // 4 KB
  for (int g = t; g < RCH*BT; g += 256) {
    const int r = g & (RCH-1), i = g >> 7;
    c_lds[r][i] = ctxacc[(size_t)(b0+i)*(NH*NE) + (size_t)h*NE + e0 + r] * rn_lds[i];
  }
  __syncthreads();

  float accv[BT];
  #pragma unroll
  for (int i = 0; i < BT; ++i) accv[i] = 0.f;
  const float* w = out_w + ((size_t)rc*RCH)*NA + a;
  #pragma unroll 8
  for (int r = 0; r < RCH; ++r) {
    float wvv = w[(size_t)r*NA];
    float4 ca = *(const float4*)&c_lds[r][0];
    float4 cb = *(const float4*)&c_lds[r][4];
    accv[0] += ca.x*wvv; accv[1] += ca.y*wvv; accv[2] += ca.z*wvv; accv[3] += ca.w*wvv;
    accv[4] += cb.x*wvv; accv[5] += cb.y*wvv; accv[6] += cb.z*wvv; accv[7] += cb.w*wvv;
  }
  #pragma unroll
  for (int i = 0; i < BT; ++i)
    unsafeAtomicAdd(&out[(size_t)(b0+i)*NA + a], accv[i]);
}

// ---------------------------------------------------------------------------
extern "C" void kernel_launch(void* const* d_in, const int* in_sizes, int n_in,
                              void* d_out, int out_size, void* d_ws, size_t ws_size,
                              hipStream_t stream) {
  const float* dec   = (const float*)d_in[0];
  const float* enc   = (const float*)d_in[1];
  const float* phi_w = (const float*)d_in[2];
  const float* phi_b = (const float*)d_in[3];
  const float* psi_w = (const float*)d_in[4];
  // d_in[5] = psi_b: constant over u -> cancels in softmax.
  const float* out_w = (const float*)d_in[6];
  const float* out_b = (const float*)d_in[7];
  float* out = (float*)d_out;
  float* ws = (float*)d_ws;
  float* q      = ws + WS_Q;
  float* ctxacc = ws + WS_CTX;
  float* P      = ws + WS_P;

  hipLaunchKernelGGL(k_phi,   dim3(NH*4*DSP),              dim3(256), 0, stream,
                     dec, phi_w, P, q, ctxacc, out_b, out);
  hipLaunchKernelGGL(k_q,     dim3(128),                   dim3(256), 0, stream,
                     P, phi_b, psi_w, q);
  hipLaunchKernelGGL(k_flash, dim3(NS, NB),                dim3(256), 0, stream,
                     enc, q, ctxacc);
  hipLaunchKernelGGL(k_out,   dim3(NA/256, NB/BT, RSPLIT), dim3(256), 0, stream,
                     ctxacc, out_w, out);
}

// Round 5
// 80.667 us; speedup vs baseline: 3.1370x; 1.1303x over previous
//
#include <hip/hip_runtime.h>
#include <math.h>

typedef float f2 __attribute__((ext_vector_type(2)));

// Problem constants
constexpr int NB = 64;      // batch
constexpr int NU = 2048;    // U
constexpr int ND = 1024;    // dec dim
constexpr int NE = 512;     // enc dim
constexpr int NH = 4;       // heads
constexpr int NK = 256;     // head dim
constexpr int NA = 1024;    // out dim
constexpr int NS = 16;      // U splits
constexpr int ROWS_PER_BLOCK = NU / NS;            // 128
constexpr int ROWS_PER_WAVE  = ROWS_PER_BLOCK / 4; // 32
constexpr float SCALE = 0.0625f;                   // 1/sqrt(256)

constexpr int RSPLIT = 16;
constexpr int RCH = (NH*NE)/RSPLIT;  // 128
constexpr int BT = 8;

constexpr int DSP = 16;   // D splits in k_phi (64 d each)

// workspace layout (float offsets)
constexpr size_t WS_Q   = 0;                            // q:      131072 floats
constexpr size_t WS_CTX = WS_Q + (size_t)NB*NH*NE;      // ctxacc: 131072 floats
constexpr size_t WS_P   = WS_CTX + (size_t)NB*NH*NE;    // phi partials: 16*64*4*256 = 1M floats

// ---------------------------------------------------------------------------
// K1a: phi partials. (unchanged)
__global__ __launch_bounds__(256) void k_phi(
    const float* __restrict__ dec, const float* __restrict__ phi_w,
    float* __restrict__ P, float* __restrict__ q, float* __restrict__ ctxacc,
    const float* __restrict__ out_b, float* __restrict__ out)
{
  const int flat = blockIdx.x;              // 0..255
  const int kc = flat & 3;
  const int h  = (flat >> 2) & 3;
  const int ds = flat >> 4;                 // 0..15
  const int t = threadIdx.x;

  // replay-safe inits (consumed by later kernels; kernel boundary orders them)
  ctxacc[(size_t)flat*512 + t]       = 0.f;
  ctxacc[(size_t)flat*512 + 256 + t] = 0.f;
  q[(size_t)flat*512 + t]            = 0.f;
  q[(size_t)flat*512 + 256 + t]      = 0.f;
  out[(size_t)flat*256 + t] = out_b[(flat*256 + t) & (NA-1)];

  const int d0 = ds*64, k0 = kc*64;

  __shared__ float phi_lds[64][64];   // 16 KB [d][k]
  __shared__ float dec_t[64][68];     // 17 KB [d][b]

  {
    const int kq = t & 15, r = t >> 4;        // r: 0..15
    const float* pwb = phi_w + ((size_t)h*ND + d0)*NK + k0;
    #pragma unroll
    for (int p = 0; p < 4; ++p) {
      float4 v = *(const float4*)(pwb + (size_t)(r + 16*p)*NK + 4*kq);
      *(float4*)&phi_lds[r + 16*p][4*kq] = v;
    }
    const float* db = dec + d0 + 4*kq;
    #pragma unroll
    for (int p = 0; p < 4; ++p) {
      const int b = r + 16*p;
      float4 v = *(const float4*)(db + (size_t)b*ND);
      dec_t[4*kq+0][b] = v.x; dec_t[4*kq+1][b] = v.y;
      dec_t[4*kq+2][b] = v.z; dec_t[4*kq+3][b] = v.w;
    }
  }
  __syncthreads();

  const int k = t & 63, bq = t >> 6, b0 = bq*16;
  f2 acc2[8];
  #pragma unroll
  for (int i = 0; i < 8; ++i) acc2[i] = f2{0.f, 0.f};
  #pragma unroll 4
  for (int d = 0; d < 64; ++d) {
    float w = phi_lds[d][k];
    f2 ww = f2{w, w};
    float4 a0 = *(const float4*)&dec_t[d][b0];
    float4 a1 = *(const float4*)&dec_t[d][b0+4];
    float4 a2 = *(const float4*)&dec_t[d][b0+8];
    float4 a3 = *(const float4*)&dec_t[d][b0+12];
    acc2[0] += f2{a0.x,a0.y}*ww; acc2[1] += f2{a0.z,a0.w}*ww;
    acc2[2] += f2{a1.x,a1.y}*ww; acc2[3] += f2{a1.z,a1.w}*ww;
    acc2[4] += f2{a2.x,a2.y}*ww; acc2[5] += f2{a2.z,a2.w}*ww;
    acc2[6] += f2{a3.x,a3.y}*ww; acc2[7] += f2{a3.z,a3.w}*ww;
  }
  float* pb = P + (((size_t)ds*64 + b0)*NH + h)*NK + k0 + k;
  #pragma unroll
  for (int j = 0; j < 8; ++j) {
    pb[(size_t)(2*j  )*NH*NK] = acc2[j][0];
    pb[(size_t)(2*j+1)*NH*NK] = acc2[j][1];
  }
}

// ---------------------------------------------------------------------------
// K1b: (unchanged)
__global__ __launch_bounds__(256) void k_q(
    const float* __restrict__ P, const float* __restrict__ phi_b,
    const float* __restrict__ psi_w, float* __restrict__ q)
{
  const int flat = blockIdx.x;              // 0..127
  const int ks = flat & 3;
  const int ec = (flat >> 2) & 7;
  const int h  = flat >> 5;
  const int t = threadIdx.x;
  const int k0 = ks*64, e0 = ec*64;

  __shared__ float phi_red[64][68];   // [k][b]
  __shared__ float psi_lds[64][65];   // [e][k]

  {
    const int e = t >> 2, kq4 = t & 3;
    const float* pb = psi_w + ((size_t)h*NE + e0 + e)*NK + k0 + 4*kq4;
    #pragma unroll
    for (int p = 0; p < 4; ++p) {
      float4 v = *(const float4*)(pb + 16*p);
      const int kk = 4*(kq4 + 4*p);
      psi_lds[e][kk+0] = v.x; psi_lds[e][kk+1] = v.y;
      psi_lds[e][kk+2] = v.z; psi_lds[e][kk+3] = v.w;
    }
  }
  {
    const int b = t >> 2, kq4 = t & 3;
    const float* pbase = P + ((size_t)b*NH + h)*NK + k0 + 4*kq4;
    #pragma unroll
    for (int p = 0; p < 4; ++p) {
      float4 s = make_float4(0.f, 0.f, 0.f, 0.f);
      #pragma unroll
      for (int dsi = 0; dsi < DSP; ++dsi) {
        float4 v = *(const float4*)(pbase + (size_t)dsi*64*NH*NK + 16*p);
        s.x += v.x; s.y += v.y; s.z += v.z; s.w += v.w;
      }
      const int kk = 4*(kq4 + 4*p);
      const float* bb = phi_b + h*NK + k0 + kk;
      phi_red[kk+0][b] = s.x + bb[0];
      phi_red[kk+1][b] = s.y + bb[1];
      phi_red[kk+2][b] = s.z + bb[2];
      phi_red[kk+3][b] = s.w + bb[3];
    }
  }
  __syncthreads();

  const int e = t & 63, bq = t >> 6, b0 = bq*16;
  f2 acc2[8];
  #pragma unroll
  for (int i = 0; i < 8; ++i) acc2[i] = f2{0.f, 0.f};
  #pragma unroll 4
  for (int kl = 0; kl < 64; ++kl) {
    float w = psi_lds[e][kl];
    f2 ww = f2{w, w};
    float4 a0 = *(const float4*)&phi_red[kl][b0];
    float4 a1 = *(const float4*)&phi_red[kl][b0+4];
    float4 a2 = *(const float4*)&phi_red[kl][b0+8];
    float4 a3 = *(const float4*)&phi_red[kl][b0+12];
    acc2[0] += f2{a0.x,a0.y}*ww; acc2[1] += f2{a0.z,a0.w}*ww;
    acc2[2] += f2{a1.x,a1.y}*ww; acc2[3] += f2{a1.z,a1.w}*ww;
    acc2[4] += f2{a2.x,a2.y}*ww; acc2[5] += f2{a2.z,a2.w}*ww;
    acc2[6] += f2{a3.x,a3.y}*ww; acc2[7] += f2{a3.z,a3.w}*ww;
  }
  float* qb = q + ((size_t)b0*NH + h)*NE + e0 + e;
  #pragma unroll
  for (int j = 0; j < 8; ++j) {
    unsafeAtomicAdd(qb + (size_t)(2*j  )*NH*NE, acc2[j][0]);
    unsafeAtomicAdd(qb + (size_t)(2*j+1)*NH*NE, acc2[j][1]);
  }
}

// ---------------------------------------------------------------------------
// K2 v4: DS-pipe relief. Wave = 2 half-waves; each 32-lane half owns one row
// of a row pair; each lane owns 16 e-cols (4 x float4, 512B-contiguous per
// half -> coalesced). Dot reduce = 5 shuffle steps over 32 lanes, 2 rows per
// pass -> 10 shuffles/row (was 24+). After reduce every lane has its row's
// weight AND its own enc cols -> PV needs no broadcast, no LDS in hot loop.
// Manual depth-1 prefetch straight to registers. Cross-half combine via one
// xor-32 shuffle set in the epilogue.
__device__ __forceinline__ f2 shflx(f2 v, int m) {
  return f2{__shfl_xor(v[0], m), __shfl_xor(v[1], m)};
}

__global__ __launch_bounds__(256) void k_flash(
    const float* __restrict__ enc, const float* __restrict__ qg,
    float* __restrict__ ctxacc)
{
  const int s = blockIdx.x;
  const int b = blockIdx.y;
  const int t = threadIdx.x;
  const int wave = t >> 6;
  const int lane = t & 63;
  const int half = lane >> 5;     // which row of the pair
  const int l32 = lane & 31;

  // q fragments, SCALE folded: lane owns cols {ch*128 + l32*4 .. +3}, ch=0..3
  f2 qv[NH][8];
  const float* qbase = qg + (size_t)b*NH*NE + 4*l32;
  #pragma unroll
  for (int h = 0; h < NH; ++h)
    #pragma unroll
    for (int ch = 0; ch < 4; ++ch) {
      float4 a = *(const float4*)(qbase + h*NE + ch*128);
      qv[h][2*ch]   = f2{a.x*SCALE, a.y*SCALE};
      qv[h][2*ch+1] = f2{a.z*SCALE, a.w*SCALE};
    }

  f2 acc2[NH][8];
  #pragma unroll
  for (int h = 0; h < NH; ++h)
    #pragma unroll
    for (int j = 0; j < 8; ++j) acc2[h][j] = f2{0.f, 0.f};

  const int u0 = s*ROWS_PER_BLOCK + wave*ROWS_PER_WAVE;
  // this lane's row stream: rows u0 + 2*i + half, its 16 cols
  const float* myrow = enc + ((size_t)b*NU + u0 + half)*NE + 4*l32;

#define FLOAD(d0_, d1_, d2_, d3_, it) { \
    const float* rp_ = myrow + (size_t)(it)*2*NE; \
    d0_ = *(const float4*)(rp_);       d1_ = *(const float4*)(rp_ + 128); \
    d2_ = *(const float4*)(rp_ + 256); d3_ = *(const float4*)(rp_ + 384); }

#define FCOMP(x0, x1, x2, x3) { \
    f2 p0 = f2{x0.x,x0.y}*qv[0][0] + f2{x0.z,x0.w}*qv[0][1] \
          + f2{x1.x,x1.y}*qv[0][2] + f2{x1.z,x1.w}*qv[0][3] \
          + f2{x2.x,x2.y}*qv[0][4] + f2{x2.z,x2.w}*qv[0][5] \
          + f2{x3.x,x3.y}*qv[0][6] + f2{x3.z,x3.w}*qv[0][7]; \
    f2 p1 = f2{x0.x,x0.y}*qv[1][0] + f2{x0.z,x0.w}*qv[1][1] \
          + f2{x1.x,x1.y}*qv[1][2] + f2{x1.z,x1.w}*qv[1][3] \
          + f2{x2.x,x2.y}*qv[1][4] + f2{x2.z,x2.w}*qv[1][5] \
          + f2{x3.x,x3.y}*qv[1][6] + f2{x3.z,x3.w}*qv[1][7]; \
    f2 p2 = f2{x0.x,x0.y}*qv[2][0] + f2{x0.z,x0.w}*qv[2][1] \
          + f2{x1.x,x1.y}*qv[2][2] + f2{x1.z,x1.w}*qv[2][3] \
          + f2{x2.x,x2.y}*qv[2][4] + f2{x2.z,x2.w}*qv[2][5] \
          + f2{x3.x,x3.y}*qv[2][6] + f2{x3.z,x3.w}*qv[2][7]; \
    f2 p3 = f2{x0.x,x0.y}*qv[3][0] + f2{x0.z,x0.w}*qv[3][1] \
          + f2{x1.x,x1.y}*qv[3][2] + f2{x1.z,x1.w}*qv[3][3] \
          + f2{x2.x,x2.y}*qv[3][4] + f2{x2.z,x2.w}*qv[3][5] \
          + f2{x3.x,x3.y}*qv[3][6] + f2{x3.z,x3.w}*qv[3][7]; \
    f2 d01 = f2{p0[0]+p0[1], p1[0]+p1[1]}; \
    f2 d23 = f2{p2[0]+p2[1], p3[0]+p3[1]}; \
    d01 += shflx(d01, 1);  d23 += shflx(d23, 1); \
    d01 += shflx(d01, 2);  d23 += shflx(d23, 2); \
    d01 += shflx(d01, 4);  d23 += shflx(d23, 4); \
    d01 += shflx(d01, 8);  d23 += shflx(d23, 8); \
    d01 += shflx(d01, 16); d23 += shflx(d23, 16); \
    float w0 = __expf(d01[0]), w1 = __expf(d01[1]); \
    float w2 = __expf(d23[0]), w3 = __expf(d23[1]); \
    acc2[0][0]+=f2{w0,w0}*f2{x0.x,x0.y}; acc2[0][1]+=f2{w0,w0}*f2{x0.z,x0.w}; \
    acc2[0][2]+=f2{w0,w0}*f2{x1.x,x1.y}; acc2[0][3]+=f2{w0,w0}*f2{x1.z,x1.w}; \
    acc2[0][4]+=f2{w0,w0}*f2{x2.x,x2.y}; acc2[0][5]+=f2{w0,w0}*f2{x2.z,x2.w}; \
    acc2[0][6]+=f2{w0,w0}*f2{x3.x,x3.y}; acc2[0][7]+=f2{w0,w0}*f2{x3.z,x3.w}; \
    acc2[1][0]+=f2{w1,w1}*f2{x0.x,x0.y}; acc2[1][1]+=f2{w1,w1}*f2{x0.z,x0.w}; \
    acc2[1][2]+=f2{w1,w1}*f2{x1.x,x1.y}; acc2[1][3]+=f2{w1,w1}*f2{x1.z,x1.w}; \
    acc2[1][4]+=f2{w1,w1}*f2{x2.x,x2.y}; acc2[1][5]+=f2{w1,w1}*f2{x2.z,x2.w}; \
    acc2[1][6]+=f2{w1,w1}*f2{x3.x,x3.y}; acc2[1][7]+=f2{w1,w1}*f2{x3.z,x3.w}; \
    acc2[2][0]+=f2{w2,w2}*f2{x0.x,x0.y}; acc2[2][1]+=f2{w2,w2}*f2{x0.z,x0.w}; \
    acc2[2][2]+=f2{w2,w2}*f2{x1.x,x1.y}; acc2[2][3]+=f2{w2,w2}*f2{x1.z,x1.w}; \
    acc2[2][4]+=f2{w2,w2}*f2{x2.x,x2.y}; acc2[2][5]+=f2{w2,w2}*f2{x2.z,x2.w}; \
    acc2[2][6]+=f2{w2,w2}*f2{x3.x,x3.y}; acc2[2][7]+=f2{w2,w2}*f2{x3.z,x3.w}; \
    acc2[3][0]+=f2{w3,w3}*f2{x0.x,x0.y}; acc2[3][1]+=f2{w3,w3}*f2{x0.z,x0.w}; \
    acc2[3][2]+=f2{w3,w3}*f2{x1.x,x1.y}; acc2[3][3]+=f2{w3,w3}*f2{x1.z,x1.w}; \
    acc2[3][4]+=f2{w3,w3}*f2{x2.x,x2.y}; acc2[3][5]+=f2{w3,w3}*f2{x2.z,x2.w}; \
    acc2[3][6]+=f2{w3,w3}*f2{x3.x,x3.y}; acc2[3][7]+=f2{w3,w3}*f2{x3.z,x3.w}; }

  float4 A0,A1,A2,A3, B0,B1,B2,B3;
  FLOAD(A0,A1,A2,A3, 0)
  #pragma unroll 2
  for (int i = 0; i < ROWS_PER_WAVE/2; i += 2) {
    if (i + 1 < ROWS_PER_WAVE/2) FLOAD(B0,B1,B2,B3, i+1)
    FCOMP(A0,A1,A2,A3)
    if (i + 2 < ROWS_PER_WAVE/2) FLOAD(A0,A1,A2,A3, i+2)
    if (i + 1 < ROWS_PER_WAVE/2) FCOMP(B0,B1,B2,B3)
  }
#undef FLOAD
#undef FCOMP

  // combine the two halves (same cols, different row sets): one-time shuffles
  #pragma unroll
  for (int h = 0; h < NH; ++h)
    #pragma unroll
    for (int j = 0; j < 8; ++j) acc2[h][j] += shflx(acc2[h][j], 32);

  // cross-wave reduce via LDS, then one atomicAdd per (h,e)
  __shared__ float acc_lds[4*NH*NE];   // 32 KB
  if (half == 0) {
    #pragma unroll
    for (int h = 0; h < NH; ++h)
      #pragma unroll
      for (int ch = 0; ch < 4; ++ch)
        *(float4*)&acc_lds[(wave*NH + h)*NE + ch*128 + 4*l32] =
            make_float4(acc2[h][2*ch][0], acc2[h][2*ch][1],
                        acc2[h][2*ch+1][0], acc2[h][2*ch+1][1]);
  }
  __syncthreads();
  float* cb = ctxacc + (size_t)b*(NH*NE);
  #pragma unroll
  for (int h = 0; h < NH; ++h) {
    #pragma unroll
    for (int eo = 0; eo < 2; ++eo) {
      int e = t + eo*256;
      float v = acc_lds[(0*NH + h)*NE + e] + acc_lds[(1*NH + h)*NE + e]
              + acc_lds[(2*NH + h)*NE + e] + acc_lds[(3*NH + h)*NE + e];
      unsafeAtomicAdd(&cb[h*NE + e], v);
    }
  }
}

// ---------------------------------------------------------------------------
// K3: (unchanged)
__global__ __launch_bounds__(256) void k_out(
    const float* __restrict__ ctxacc, const float* __restrict__ out_w,
    float* __restrict__ out)
{
  const int t = threadIdx.x;
  const int a = blockIdx.x*256 + t;
  const int b0 = blockIdx.y * BT;
  const int rc = blockIdx.z;
  const int h  = rc >> 2;
  const int e0 = (rc & 3) * RCH;

  __shared__ float rn_lds[BT];
  const int wv = t >> 6, lane = t & 63;
  {
    const int i = 2*wv + (lane >> 5);
    const int l32 = lane & 31;
    const float* row = ctxacc + (size_t)(b0+i)*(NH*NE) + (size_t)h*NE;
    float ss = 0.f;
    #pragma unroll
    for (int j = 0; j < 16; ++j) { float v = row[l32 + 32*j]; ss += v*v; }
    #pragma unroll
    for (int off = 1; off < 32; off <<= 1) ss += __shfl_xor(ss, off);
    if (l32 == 0) rn_lds[i] = rsqrtf(fmaxf(ss, 1e-12f));
  }
  __syncthreads();

  __shared__ float c_lds[RCH][BT];   // 4 KB
  for (int g = t; g < RCH*BT; g += 256) {
    const int r = g & (RCH-1), i = g >> 7;
    c_lds[r][i] = ctxacc[(size_t)(b0+i)*(NH*NE) + (size_t)h*NE + e0 + r] * rn_lds[i];
  }
  __syncthreads();

  float accv[BT];
  #pragma unroll
  for (int i = 0; i < BT; ++i) accv[i] = 0.f;
  const float* w = out_w + ((size_t)rc*RCH)*NA + a;
  #pragma unroll 8
  for (int r = 0; r < RCH; ++r) {
    float wvv = w[(size_t)r*NA];
    float4 ca = *(const float4*)&c_lds[r][0];
    float4 cb = *(const float4*)&c_lds[r][4];
    accv[0] += ca.x*wvv; accv[1] += ca.y*wvv; accv[2] += ca.z*wvv; accv[3] += ca.w*wvv;
    accv[4] += cb.x*wvv; accv[5] += cb.y*wvv; accv[6] += cb.z*wvv; accv[7] += cb.w*wvv;
  }
  #pragma unroll
  for (int i = 0; i < BT; ++i)
    unsafeAtomicAdd(&out[(size_t)(b0+i)*NA + a], accv[i]);
}

// ---------------------------------------------------------------------------
extern "C" void kernel_launch(void* const* d_in, const int* in_sizes, int n_in,
                              void* d_out, int out_size, void* d_ws, size_t ws_size,
                              hipStream_t stream) {
  const float* dec   = (const float*)d_in[0];
  const float* enc   = (const float*)d_in[1];
  const float* phi_w = (const float*)d_in[2];
  const float* phi_b = (const float*)d_in[3];
  const float* psi_w = (const float*)d_in[4];
  // d_in[5] = psi_b: constant over u -> cancels in softmax.
  const float* out_w = (const float*)d_in[6];
  const float* out_b = (const float*)d_in[7];
  float* out = (float*)d_out;
  float* ws = (float*)d_ws;
  float* q      = ws + WS_Q;
  float* ctxacc = ws + WS_CTX;
  float* P      = ws + WS_P;

  hipLaunchKernelGGL(k_phi,   dim3(NH*4*DSP),              dim3(256), 0, stream,
                     dec, phi_w, P, q, ctxacc, out_b, out);
  hipLaunchKernelGGL(k_q,     dim3(128),                   dim3(256), 0, stream,
                     P, phi_b, psi_w, q);
  hipLaunchKernelGGL(k_flash, dim3(NS, NB),                dim3(256), 0, stream,
                     enc, q, ctxacc);
  hipLaunchKernelGGL(k_out,   dim3(NA/256, NB/BT, RSPLIT), dim3(256), 0, stream,
                     ctxacc, out_w, out);
}

// Round 6
// 79.900 us; speedup vs baseline: 3.1671x; 1.0096x over previous
//
#include <hip/hip_runtime.h>
#include <math.h>

typedef float f2 __attribute__((ext_vector_type(2)));

// Problem constants
constexpr int NB = 64;      // batch
constexpr int NU = 2048;    // U
constexpr int ND = 1024;    // dec dim
constexpr int NE = 512;     // enc dim
constexpr int NH = 4;       // heads
constexpr int NK = 256;     // head dim
constexpr int NA = 1024;    // out dim
constexpr int NS = 16;      // U splits
constexpr int ROWS_PER_BLOCK = NU / NS;            // 128
constexpr int ROWS_PER_WAVE  = ROWS_PER_BLOCK / 4; // 32
constexpr float SCALE = 0.0625f;                   // 1/sqrt(256)

constexpr int RSPLIT = 16;
constexpr int RCH = (NH*NE)/RSPLIT;  // 128
constexpr int BT = 8;

constexpr int DSP = 16;   // D splits in k_phi (64 d each)

// workspace layout (float offsets)
constexpr size_t WS_Q   = 0;                            // q:      131072 floats
constexpr size_t WS_CTX = WS_Q + (size_t)NB*NH*NE;      // ctxacc: 131072 floats
constexpr size_t WS_P   = WS_CTX + (size_t)NB*NH*NE;    // phi partials: 16*64*4*256 = 1M floats

// ---------------------------------------------------------------------------
// K1a: phi partials. (unchanged)
__global__ __launch_bounds__(256) void k_phi(
    const float* __restrict__ dec, const float* __restrict__ phi_w,
    float* __restrict__ P, float* __restrict__ q, float* __restrict__ ctxacc,
    const float* __restrict__ out_b, float* __restrict__ out)
{
  const int flat = blockIdx.x;              // 0..255
  const int kc = flat & 3;
  const int h  = (flat >> 2) & 3;
  const int ds = flat >> 4;                 // 0..15
  const int t = threadIdx.x;

  // replay-safe inits (consumed by later kernels; kernel boundary orders them)
  ctxacc[(size_t)flat*512 + t]       = 0.f;
  ctxacc[(size_t)flat*512 + 256 + t] = 0.f;
  q[(size_t)flat*512 + t]            = 0.f;
  q[(size_t)flat*512 + 256 + t]      = 0.f;
  out[(size_t)flat*256 + t] = out_b[(flat*256 + t) & (NA-1)];

  const int d0 = ds*64, k0 = kc*64;

  __shared__ float phi_lds[64][64];   // 16 KB [d][k]
  __shared__ float dec_t[64][68];     // 17 KB [d][b]

  {
    const int kq = t & 15, r = t >> 4;        // r: 0..15
    const float* pwb = phi_w + ((size_t)h*ND + d0)*NK + k0;
    #pragma unroll
    for (int p = 0; p < 4; ++p) {
      float4 v = *(const float4*)(pwb + (size_t)(r + 16*p)*NK + 4*kq);
      *(float4*)&phi_lds[r + 16*p][4*kq] = v;
    }
    const float* db = dec + d0 + 4*kq;
    #pragma unroll
    for (int p = 0; p < 4; ++p) {
      const int b = r + 16*p;
      float4 v = *(const float4*)(db + (size_t)b*ND);
      dec_t[4*kq+0][b] = v.x; dec_t[4*kq+1][b] = v.y;
      dec_t[4*kq+2][b] = v.z; dec_t[4*kq+3][b] = v.w;
    }
  }
  __syncthreads();

  const int k = t & 63, bq = t >> 6, b0 = bq*16;
  f2 acc2[8];
  #pragma unroll
  for (int i = 0; i < 8; ++i) acc2[i] = f2{0.f, 0.f};
  #pragma unroll 4
  for (int d = 0; d < 64; ++d) {
    float w = phi_lds[d][k];
    f2 ww = f2{w, w};
    float4 a0 = *(const float4*)&dec_t[d][b0];
    float4 a1 = *(const float4*)&dec_t[d][b0+4];
    float4 a2 = *(const float4*)&dec_t[d][b0+8];
    float4 a3 = *(const float4*)&dec_t[d][b0+12];
    acc2[0] += f2{a0.x,a0.y}*ww; acc2[1] += f2{a0.z,a0.w}*ww;
    acc2[2] += f2{a1.x,a1.y}*ww; acc2[3] += f2{a1.z,a1.w}*ww;
    acc2[4] += f2{a2.x,a2.y}*ww; acc2[5] += f2{a2.z,a2.w}*ww;
    acc2[6] += f2{a3.x,a3.y}*ww; acc2[7] += f2{a3.z,a3.w}*ww;
  }
  float* pb = P + (((size_t)ds*64 + b0)*NH + h)*NK + k0 + k;
  #pragma unroll
  for (int j = 0; j < 8; ++j) {
    pb[(size_t)(2*j  )*NH*NK] = acc2[j][0];
    pb[(size_t)(2*j+1)*NH*NK] = acc2[j][1];
  }
}

// ---------------------------------------------------------------------------
// K1b: (unchanged)
__global__ __launch_bounds__(256) void k_q(
    const float* __restrict__ P, const float* __restrict__ phi_b,
    const float* __restrict__ psi_w, float* __restrict__ q)
{
  const int flat = blockIdx.x;              // 0..127
  const int ks = flat & 3;
  const int ec = (flat >> 2) & 7;
  const int h  = flat >> 5;
  const int t = threadIdx.x;
  const int k0 = ks*64, e0 = ec*64;

  __shared__ float phi_red[64][68];   // [k][b]
  __shared__ float psi_lds[64][65];   // [e][k]

  {
    const int e = t >> 2, kq4 = t & 3;
    const float* pb = psi_w + ((size_t)h*NE + e0 + e)*NK + k0 + 4*kq4;
    #pragma unroll
    for (int p = 0; p < 4; ++p) {
      float4 v = *(const float4*)(pb + 16*p);
      const int kk = 4*(kq4 + 4*p);
      psi_lds[e][kk+0] = v.x; psi_lds[e][kk+1] = v.y;
      psi_lds[e][kk+2] = v.z; psi_lds[e][kk+3] = v.w;
    }
  }
  {
    const int b = t >> 2, kq4 = t & 3;
    const float* pbase = P + ((size_t)b*NH + h)*NK + k0 + 4*kq4;
    #pragma unroll
    for (int p = 0; p < 4; ++p) {
      float4 s = make_float4(0.f, 0.f, 0.f, 0.f);
      #pragma unroll
      for (int dsi = 0; dsi < DSP; ++dsi) {
        float4 v = *(const float4*)(pbase + (size_t)dsi*64*NH*NK + 16*p);
        s.x += v.x; s.y += v.y; s.z += v.z; s.w += v.w;
      }
      const int kk = 4*(kq4 + 4*p);
      const float* bb = phi_b + h*NK + k0 + kk;
      phi_red[kk+0][b] = s.x + bb[0];
      phi_red[kk+1][b] = s.y + bb[1];
      phi_red[kk+2][b] = s.z + bb[2];
      phi_red[kk+3][b] = s.w + bb[3];
    }
  }
  __syncthreads();

  const int e = t & 63, bq = t >> 6, b0 = bq*16;
  f2 acc2[8];
  #pragma unroll
  for (int i = 0; i < 8; ++i) acc2[i] = f2{0.f, 0.f};
  #pragma unroll 4
  for (int kl = 0; kl < 64; ++kl) {
    float w = psi_lds[e][kl];
    f2 ww = f2{w, w};
    float4 a0 = *(const float4*)&phi_red[kl][b0];
    float4 a1 = *(const float4*)&phi_red[kl][b0+4];
    float4 a2 = *(const float4*)&phi_red[kl][b0+8];
    float4 a3 = *(const float4*)&phi_red[kl][b0+12];
    acc2[0] += f2{a0.x,a0.y}*ww; acc2[1] += f2{a0.z,a0.w}*ww;
    acc2[2] += f2{a1.x,a1.y}*ww; acc2[3] += f2{a1.z,a1.w}*ww;
    acc2[4] += f2{a2.x,a2.y}*ww; acc2[5] += f2{a2.z,a2.w}*ww;
    acc2[6] += f2{a3.x,a3.y}*ww; acc2[7] += f2{a3.z,a3.w}*ww;
  }
  float* qb = q + ((size_t)b0*NH + h)*NE + e0 + e;
  #pragma unroll
  for (int j = 0; j < 8; ++j) {
    unsafeAtomicAdd(qb + (size_t)(2*j  )*NH*NE, acc2[j][0]);
    unsafeAtomicAdd(qb + (size_t)(2*j+1)*NH*NE, acc2[j][1]);
  }
}

// ---------------------------------------------------------------------------
// K2 v5: v4's half-wave structure + DEPTH-4 circular register prefetch.
// Theory: flash was MLP-bound (~32 KB in flight/CU across all prior versions
// -> ~3.5 TB/s at ~2300cy loaded latency). Depth-4 keeps 12-16 KB/wave in
// flight (vmcnt FIFO: waiting on oldest buffer leaves 12 newer loads live),
// 8 waves/CU -> ~100+ KB/CU -> HBM-bound.
__device__ __forceinline__ f2 shflx(f2 v, int m) {
  return f2{__shfl_xor(v[0], m), __shfl_xor(v[1], m)};
}

__device__ __forceinline__ void fload(float4 (&r)[4], const float* myrow, int it) {
  const float* rp = myrow + (size_t)it*2*NE;
  r[0] = *(const float4*)(rp);
  r[1] = *(const float4*)(rp + 128);
  r[2] = *(const float4*)(rp + 256);
  r[3] = *(const float4*)(rp + 384);
}

__device__ __forceinline__ void fcomp(const float4 (&x)[4],
                                      const f2 (&qv)[NH][8], f2 (&acc2)[NH][8]) {
  f2 xf[8];
  xf[0]=f2{x[0].x,x[0].y}; xf[1]=f2{x[0].z,x[0].w};
  xf[2]=f2{x[1].x,x[1].y}; xf[3]=f2{x[1].z,x[1].w};
  xf[4]=f2{x[2].x,x[2].y}; xf[5]=f2{x[2].z,x[2].w};
  xf[6]=f2{x[3].x,x[3].y}; xf[7]=f2{x[3].z,x[3].w};
  f2 p[NH];
  #pragma unroll
  for (int h = 0; h < NH; ++h) {
    p[h] = xf[0]*qv[h][0];
    #pragma unroll
    for (int j = 1; j < 8; ++j) p[h] += xf[j]*qv[h][j];
  }
  f2 d01 = f2{p[0][0]+p[0][1], p[1][0]+p[1][1]};
  f2 d23 = f2{p[2][0]+p[2][1], p[3][0]+p[3][1]};
  #pragma unroll
  for (int off = 1; off < 32; off <<= 1) {
    d01 += shflx(d01, off);
    d23 += shflx(d23, off);
  }
  const float w[NH] = {__expf(d01[0]), __expf(d01[1]),
                       __expf(d23[0]), __expf(d23[1])};
  #pragma unroll
  for (int h = 0; h < NH; ++h) {
    f2 ww = f2{w[h], w[h]};
    #pragma unroll
    for (int j = 0; j < 8; ++j) acc2[h][j] += ww*xf[j];
  }
}

__global__ __launch_bounds__(256) void k_flash(
    const float* __restrict__ enc, const float* __restrict__ qg,
    float* __restrict__ ctxacc)
{
  const int s = blockIdx.x;
  const int b = blockIdx.y;
  const int t = threadIdx.x;
  const int wave = t >> 6;
  const int lane = t & 63;
  const int half = lane >> 5;     // which row of the pair
  const int l32 = lane & 31;

  // q fragments, SCALE folded: lane owns cols {ch*128 + l32*4 .. +3}, ch=0..3
  f2 qv[NH][8];
  const float* qbase = qg + (size_t)b*NH*NE + 4*l32;
  #pragma unroll
  for (int h = 0; h < NH; ++h)
    #pragma unroll
    for (int ch = 0; ch < 4; ++ch) {
      float4 a = *(const float4*)(qbase + h*NE + ch*128);
      qv[h][2*ch]   = f2{a.x*SCALE, a.y*SCALE};
      qv[h][2*ch+1] = f2{a.z*SCALE, a.w*SCALE};
    }

  f2 acc2[NH][8];
  #pragma unroll
  for (int h = 0; h < NH; ++h)
    #pragma unroll
    for (int j = 0; j < 8; ++j) acc2[h][j] = f2{0.f, 0.f};

  const int u0 = s*ROWS_PER_BLOCK + wave*ROWS_PER_WAVE;
  // this lane's row stream: rows u0 + 2*i + half, its 16 cols
  const float* myrow = enc + ((size_t)b*NU + u0 + half)*NE + 4*l32;

  constexpr int NIT = ROWS_PER_WAVE/2;   // 16 row-pair iterations
  float4 R[4][4];                        // circular depth-4 buffer (64 VGPR)
  #pragma unroll
  for (int c = 0; c < 4; ++c) fload(R[c], myrow, c);
  #pragma unroll
  for (int i = 0; i < NIT; ++i) {        // full unroll: all R-indices static
    fcomp(R[i & 3], qv, acc2);
    if (i + 4 < NIT) fload(R[i & 3], myrow, i + 4);
  }

  // combine the two halves (same cols, different row sets): one-time shuffles
  #pragma unroll
  for (int h = 0; h < NH; ++h)
    #pragma unroll
    for (int j = 0; j < 8; ++j) acc2[h][j] += shflx(acc2[h][j], 32);

  // cross-wave reduce via LDS, then one atomicAdd per (h,e)
  __shared__ float acc_lds[4*NH*NE];   // 32 KB
  if (half == 0) {
    #pragma unroll
    for (int h = 0; h < NH; ++h)
      #pragma unroll
      for (int ch = 0; ch < 4; ++ch)
        *(float4*)&acc_lds[(wave*NH + h)*NE + ch*128 + 4*l32] =
            make_float4(acc2[h][2*ch][0], acc2[h][2*ch][1],
                        acc2[h][2*ch+1][0], acc2[h][2*ch+1][1]);
  }
  __syncthreads();
  float* cb = ctxacc + (size_t)b*(NH*NE);
  #pragma unroll
  for (int h = 0; h < NH; ++h) {
    #pragma unroll
    for (int eo = 0; eo < 2; ++eo) {
      int e = t + eo*256;
      float v = acc_lds[(0*NH + h)*NE + e] + acc_lds[(1*NH + h)*NE + e]
              + acc_lds[(2*NH + h)*NE + e] + acc_lds[(3*NH + h)*NE + e];
      unsafeAtomicAdd(&cb[h*NE + e], v);
    }
  }
}

// ---------------------------------------------------------------------------
// K3: (unchanged)
__global__ __launch_bounds__(256) void k_out(
    const float* __restrict__ ctxacc, const float* __restrict__ out_w,
    float* __restrict__ out)
{
  const int t = threadIdx.x;
  const int a = blockIdx.x*256 + t;
  const int b0 = blockIdx.y * BT;
  const int rc = blockIdx.z;
  const int h  = rc >> 2;
  const int e0 = (rc & 3) * RCH;

  __shared__ float rn_lds[BT];
  const int wv = t >> 6, lane = t & 63;
  {
    const int i = 2*wv + (lane >> 5);
    const int l32 = lane & 31;
    const float* row = ctxacc + (size_t)(b0+i)*(NH*NE) + (size_t)h*NE;
    float ss = 0.f;
    #pragma unroll
    for (int j = 0; j < 16; ++j) { float v = row[l32 + 32*j]; ss += v*v; }
    #pragma unroll
    for (int off = 1; off < 32; off <<= 1) ss += __shfl_xor(ss, off);
    if (l32 == 0) rn_lds[i] = rsqrtf(fmaxf(ss, 1e-12f));
  }
  __syncthreads();

  __shared__ float c_lds[RCH][BT];   // 4 KB
  for (int g = t; g < RCH*BT; g += 256) {
    const int r = g & (RCH-1), i = g >> 7;
    c_lds[r][i] = ctxacc[(size_t)(b0+i)*(NH*NE) + (size_t)h*NE + e0 + r] * rn_lds[i];
  }
  __syncthreads();

  float accv[BT];
  #pragma unroll
  for (int i = 0; i < BT; ++i) accv[i] = 0.f;
  const float* w = out_w + ((size_t)rc*RCH)*NA + a;
  #pragma unroll 8
  for (int r = 0; r < RCH; ++r) {
    float wvv = w[(size_t)r*NA];
    float4 ca = *(const float4*)&c_lds[r][0];
    float4 cb = *(const float4*)&c_lds[r][4];
    accv[0] += ca.x*wvv; accv[1] += ca.y*wvv; accv[2] += ca.z*wvv; accv[3] += ca.w*wvv;
    accv[4] += cb.x*wvv; accv[5] += cb.y*wvv; accv[6] += cb.z*wvv; accv[7] += cb.w*wvv;
  }
  #pragma unroll
  for (int i = 0; i < BT; ++i)
    unsafeAtomicAdd(&out[(size_t)(b0+i)*NA + a], accv[i]);
}

// ---------------------------------------------------------------------------
extern "C" void kernel_launch(void* const* d_in, const int* in_sizes, int n_in,
                              void* d_out, int out_size, void* d_ws, size_t ws_size,
                              hipStream_t stream) {
  const float* dec   = (const float*)d_in[0];
  const float* enc   = (const float*)d_in[1];
  const float* phi_w = (const float*)d_in[2];
  const float* phi_b = (const float*)d_in[3];
  const float* psi_w = (const float*)d_in[4];
  // d_in[5] = psi_b: constant over u -> cancels in softmax.
  const float* out_w = (const float*)d_in[6];
  const float* out_b = (const float*)d_in[7];
  float* out = (float*)d_out;
  float* ws = (float*)d_ws;
  float* q      = ws + WS_Q;
  float* ctxacc = ws + WS_CTX;
  float* P      = ws + WS_P;

  hipLaunchKernelGGL(k_phi,   dim3(NH*4*DSP),              dim3(256), 0, stream,
                     dec, phi_w, P, q, ctxacc, out_b, out);
  hipLaunchKernelGGL(k_q,     dim3(128),                   dim3(256), 0, stream,
                     P, phi_b, psi_w, q);
  hipLaunchKernelGGL(k_flash, dim3(NS, NB),                dim3(256), 0, stream,
                     enc, q, ctxacc);
  hipLaunchKernelGGL(k_out,   dim3(NA/256, NB/BT, RSPLIT), dim3(256), 0, stream,
                     ctxacc, out_w, out);
}